// Round 6
// baseline (787.491 us; speedup 1.0000x reference)
//
#include <hip/hip_runtime.h>
#include <cstdint>
#include <cstddef>

#define DEV static __device__ __forceinline__

typedef __attribute__((ext_vector_type(8))) __bf16 bf16x8;
typedef __attribute__((ext_vector_type(8))) unsigned short u16x8;
typedef __attribute__((ext_vector_type(4))) float f32x4;

#define BB 4
#define SS 2048
#define DD 1024
#define HH 16
#define DH 64
#define SK 2049  // S+1 with sink token at position 0
#define LOG2E 1.4426950408889634f

DEV unsigned short f2bf(float f) {
  unsigned int u = __builtin_bit_cast(unsigned int, f);
  u += 0x7fffu + ((u >> 16) & 1u);  // RNE
  return (unsigned short)(u >> 16);
}
DEV float bf2f(unsigned short h) {
  unsigned int u = ((unsigned int)h) << 16;
  return __builtin_bit_cast(float, u);
}

DEV void gl_lds16(const void* g, void* l) {
  // async global->LDS, 16B per lane; LDS dest = wave-uniform base + lane*16
  __builtin_amdgcn_global_load_lds(
      (const __attribute__((address_space(1))) void*)g,
      (__attribute__((address_space(3))) void*)l, 16, 0, 0);
}

DEV f32x4 mfma_bf16(bf16x8 a, bf16x8 b, f32x4 c) {
  return __builtin_amdgcn_mfma_f32_16x16x32_bf16(a, b, c, 0, 0, 0);
}

// ---------------- fused prologue: converts + sink + bias prescale ----------------
// blocks [0,8192): query fp32->bf16 (4 elems/thread)
// blocks [8192,12288): W{q,k,v,o} fp32->bf16 into Wqkv / Wo
// blocks [12288,12304): sink K/V rows + bias*log2e
__global__ __launch_bounds__(256) void k_prologue(const float* __restrict__ query,
                                                  const float* __restrict__ w0,
                                                  const float* __restrict__ w1,
                                                  const float* __restrict__ w2,
                                                  const float* __restrict__ w3,
                                                  const float* __restrict__ lk,
                                                  const float* __restrict__ lv,
                                                  const float* __restrict__ bias,
                                                  unsigned short* __restrict__ Qbf,
                                                  unsigned short* __restrict__ wqkv,
                                                  unsigned short* __restrict__ wo,
                                                  unsigned short* __restrict__ Kh,
                                                  unsigned short* __restrict__ Vh,
                                                  float* __restrict__ biasL) {
  const int bid = blockIdx.x, tid = threadIdx.x;
  if (bid < 8192) {
    int i = bid * 256 + tid;
    float4 v = reinterpret_cast<const float4*>(query)[i];
    ushort4 o;
    o.x = f2bf(v.x); o.y = f2bf(v.y); o.z = f2bf(v.z); o.w = f2bf(v.w);
    reinterpret_cast<ushort4*>(Qbf)[i] = o;
  } else if (bid < 12288) {
    int i = (bid - 8192) * 256 + tid;
    int e = i * 4;                 // element index in 4x(1024*1024) space
    int sec = e >> 20;             // 0=Wq 1=Wk 2=Wv 3=Wo
    int off = e & 1048575;
    const float* s = (sec == 0) ? w0 : (sec == 1) ? w1 : (sec == 2) ? w2 : w3;
    float4 v = *reinterpret_cast<const float4*>(s + off);
    ushort4 o;
    o.x = f2bf(v.x); o.y = f2bf(v.y); o.z = f2bf(v.z); o.w = f2bf(v.w);
    unsigned short* d = (sec < 3) ? (wqkv + (size_t)sec * 1048576 + off) : (wo + off);
    *reinterpret_cast<ushort4*>(d) = o;
  } else {
    int t = (bid - 12288) * 256 + tid;  // 4096 = B*H*64
    int bh = t >> 6, d = t & 63;
    int h = bh & (HH - 1);
    Kh[(size_t)bh * SK * DH + d] = f2bf(lk[h * DH + d]);
    Vh[(size_t)bh * SK * DH + d] = f2bf(lv[h * DH + d]);
    biasL[t] = bias[t] * LOG2E;
    biasL[t + 4096] = bias[t + 4096] * LOG2E;
  }
}

// ---------------- GEMM (m97 structure): C[m,n] = sum_k A[m,k]*Bw[n,k] ----------------
// A:[M,1024] bf16, Bw:[N,1024] bf16 (B^T form). 128x128 tile, BK=32, 4 waves.
// 1-D grid with XCD-aware swizzle (T1): each XCD gets an m-major contiguous chunk.

__global__ __launch_bounds__(256) void k_gemm_qkv(const unsigned short* __restrict__ A,
                                                  const unsigned short* __restrict__ Bw,
                                                  const float* __restrict__ bq,
                                                  const float* __restrict__ bk,
                                                  const float* __restrict__ bv,
                                                  unsigned short* __restrict__ Qh,
                                                  unsigned short* __restrict__ Kh,
                                                  unsigned short* __restrict__ Vh) {
  __shared__ unsigned short As[128 * 32];
  __shared__ unsigned short Bs[128 * 32];
  const int tid = threadIdx.x, lane = tid & 63, wid = tid >> 6;
  const int g = lane >> 4, l15 = lane & 15;
  // XCD swizzle: 1536 blocks, 192/XCD, m-major (A-panel L2-resident)
  const int id = blockIdx.x;
  const int wk = (id & 7) * 192 + (id >> 3);
  const int m0 = (wk / 24) * 128, n0 = (wk % 24) * 128;
  const int wr = (wid >> 1) * 64, wc = (wid & 1) * 64;

  f32x4 acc[4][4] = {};

  for (int k0 = 0; k0 < 1024; k0 += 32) {
    __syncthreads();
#pragma unroll
    for (int i = 0; i < 2; ++i) {
      int e = i * 2048 + wid * 512 + lane * 8;
      int r = e >> 5, c = e & 31;
      gl_lds16(A + (size_t)(m0 + r) * 1024 + k0 + c, &As[i * 2048 + wid * 512]);
      gl_lds16(Bw + (size_t)(n0 + r) * 1024 + k0 + c, &Bs[i * 2048 + wid * 512]);
    }
    __syncthreads();  // drains vmcnt before barrier
    bf16x8 af[4], bf[4];
#pragma unroll
    for (int m = 0; m < 4; ++m)
      af[m] = *reinterpret_cast<const bf16x8*>(&As[(wr + m * 16 + l15) * 32 + g * 8]);
#pragma unroll
    for (int n = 0; n < 4; ++n)
      bf[n] = *reinterpret_cast<const bf16x8*>(&Bs[(wc + n * 16 + l15) * 32 + g * 8]);
#pragma unroll
    for (int m = 0; m < 4; ++m)
#pragma unroll
      for (int n = 0; n < 4; ++n)
        acc[m][n] = mfma_bf16(af[m], bf[n], acc[m][n]);
  }

  // epilogue: scatter into per-head Q/K/V, fold biases + q-scale, K/V at key+1
  // Q additionally scaled by log2e so attention softmax can use exp2 directly.
#pragma unroll
  for (int n = 0; n < 4; ++n) {
    int gn = n0 + wc + n * 16 + l15;
    int sec = gn >> 10;           // block-uniform (128 | 1024)
    int nh = gn & 1023;
    int h = nh >> 6, d = nh & 63;
    const float* bias = (sec == 0) ? bq : (sec == 1) ? bk : bv;
    float bia = bias[nh];
#pragma unroll
    for (int m = 0; m < 4; ++m) {
#pragma unroll
      for (int j = 0; j < 4; ++j) {
        int row = m0 + wr + m * 16 + g * 4 + j;
        int b = row >> 11, s = row & 2047;
        float v = acc[m][n][j] + bia;
        if (sec == 0) {
          Qh[((size_t)(b * HH + h) * SS + s) * DH + d] = f2bf(v * (0.125f * LOG2E));
        } else if (sec == 1) {
          Kh[((size_t)(b * HH + h) * SK + s + 1) * DH + d] = f2bf(v);
        } else {
          Vh[((size_t)(b * HH + h) * SK + s + 1) * DH + d] = f2bf(v);
        }
      }
    }
  }
}

__global__ __launch_bounds__(256) void k_gemm_out(const unsigned short* __restrict__ A,
                                                  const unsigned short* __restrict__ Bw,
                                                  const float* __restrict__ bo,
                                                  float* __restrict__ out) {
  __shared__ unsigned short As[128 * 32];
  __shared__ unsigned short Bs[128 * 32];
  const int tid = threadIdx.x, lane = tid & 63, wid = tid >> 6;
  const int g = lane >> 4, l15 = lane & 15;
  // XCD swizzle: 512 blocks, 64/XCD, m-major (B fully L2-resident: 2MB)
  const int id = blockIdx.x;
  const int wk = (id & 7) * 64 + (id >> 3);
  const int m0 = (wk >> 3) * 128, n0 = (wk & 7) * 128;
  const int wr = (wid >> 1) * 64, wc = (wid & 1) * 64;

  f32x4 acc[4][4] = {};

  for (int k0 = 0; k0 < 1024; k0 += 32) {
    __syncthreads();
#pragma unroll
    for (int i = 0; i < 2; ++i) {
      int e = i * 2048 + wid * 512 + lane * 8;
      int r = e >> 5, c = e & 31;
      gl_lds16(A + (size_t)(m0 + r) * 1024 + k0 + c, &As[i * 2048 + wid * 512]);
      gl_lds16(Bw + (size_t)(n0 + r) * 1024 + k0 + c, &Bs[i * 2048 + wid * 512]);
    }
    __syncthreads();
    bf16x8 af[4], bf[4];
#pragma unroll
    for (int m = 0; m < 4; ++m)
      af[m] = *reinterpret_cast<const bf16x8*>(&As[(wr + m * 16 + l15) * 32 + g * 8]);
#pragma unroll
    for (int n = 0; n < 4; ++n)
      bf[n] = *reinterpret_cast<const bf16x8*>(&Bs[(wc + n * 16 + l15) * 32 + g * 8]);
#pragma unroll
    for (int m = 0; m < 4; ++m)
#pragma unroll
      for (int n = 0; n < 4; ++n)
        acc[m][n] = mfma_bf16(af[m], bf[n], acc[m][n]);
  }

#pragma unroll
  for (int n = 0; n < 4; ++n) {
    int gn = n0 + wc + n * 16 + l15;
    float bia = bo[gn];
#pragma unroll
    for (int m = 0; m < 4; ++m) {
#pragma unroll
      for (int j = 0; j < 4; ++j) {
        int row = m0 + wr + m * 16 + g * 4 + j;
        out[(size_t)row * 1024 + gn] = acc[m][n][j] + bia;
      }
    }
  }
}

// ---------------- flash attention with sink token ----------------
// Block: 4 waves; each wave owns 32 q-rows (2 fragments) -> block = 128 q.
// KV tile = 64 keys, double-buffered K/VT, one barrier per tile.
// Bias (pre-scaled by log2e) is prefetched a tile ahead and injected as the
// MFMA C-initializer (exact: softmax shift-invariance unaffected).
// XCD swizzle: 8 consecutive (b,h) per XCD -> KV working set 4MB = one L2.
__global__ __launch_bounds__(256, 4) void k_attn(const unsigned short* __restrict__ Qh,
                                                 const unsigned short* __restrict__ Kh,
                                                 const unsigned short* __restrict__ Vh,
                                                 const float* __restrict__ biasL,
                                                 unsigned short* __restrict__ Xbf) {
  __shared__ unsigned short K_lds[2][64 * 64];   // [key][d], rows XOR-swizzled (row&7)
  __shared__ unsigned short VT[2][64 * 64];      // [d][key], double-XOR swizzled
  __shared__ unsigned short P_lds[4][16 * 64];   // per-wave P (one frag at a time)

  const int tid = threadIdx.x, lane = tid & 63, w = tid >> 6;
  const int g = lane >> 4, c = lane & 15;
  const int idx = (blockIdx.x & 7) * 128 + (blockIdx.x >> 3);  // T1 swizzle, 1024 blocks
  const int bh = idx >> 4, qt = idx & 15;
  const int b = bh >> 4, h = bh & 15;
  const int q0 = qt * 128 + w * 32;
  const size_t kvbase = (size_t)bh * SK * DH;
  const size_t bbase = (size_t)b * SS;

  // Q fragments for both 16-row halves (row = c, d = 32t + 8g + j)
  bf16x8 qf[2][2];
#pragma unroll
  for (int f = 0; f < 2; ++f)
#pragma unroll
    for (int t = 0; t < 2; ++t)
      qf[f][t] = *reinterpret_cast<const bf16x8*>(
          Qh + ((size_t)bh * SS + q0 + f * 16) * DH + (size_t)c * DH + t * 32 + g * 8);

  // sink: s0[f][j] = q_row . k_sink (bias col for sink is 0); exp2 domain
  bf16x8 kb_sink[2];
#pragma unroll
  for (int t = 0; t < 2; ++t)
    kb_sink[t] = *reinterpret_cast<const bf16x8*>(Kh + kvbase + t * 32 + g * 8);
  float l_sink[2][4], lpart[2][4];
  f32x4 o[2][4];
#pragma unroll
  for (int f = 0; f < 2; ++f) {
    f32x4 s0 = {0.f, 0.f, 0.f, 0.f};
#pragma unroll
    for (int t = 0; t < 2; ++t) s0 = mfma_bf16(qf[f][t], kb_sink[t], s0);
#pragma unroll
    for (int j = 0; j < 4; ++j) {
      l_sink[f][j] = __builtin_amdgcn_exp2f(s0[j]);
      lpart[f][j] = 0.f;
    }
  }
#pragma unroll
  for (int n = 0; n < 4; ++n) {
    float v = bf2f(Vh[kvbase + n * 16 + c]);
#pragma unroll
    for (int f = 0; f < 2; ++f)
#pragma unroll
      for (int j = 0; j < 4; ++j) o[f][n][j] = l_sink[f][j] * v;
  }

  // V prefetch state: thread owns k-rows {2kp, 2kp+1}, d-slice d0..d0+7
  const int kp = tid >> 3;          // 0..31
  const int d0 = (tid & 7) * 8;
  u16x8 pv0, pv1;

  auto stage_k = [&](int key0, unsigned short* Kdst) {
#pragma unroll
    for (int i = 0; i < 2; ++i) {
      int ob = i * 4096 + w * 1024 + lane * 16;  // dest tile byte
      int r = ob >> 7, cb = ob & 127;
      int sc = cb ^ ((r & 7) << 4);
      gl_lds16(Kh + kvbase + (size_t)(key0 + r + 1) * DH + (sc >> 1),
               (char*)Kdst + i * 4096 + w * 1024);
    }
  };
  auto load_v = [&](int key0) {
    pv0 = *reinterpret_cast<const u16x8*>(Vh + kvbase + (size_t)(key0 + kp * 2 + 1) * DH + d0);
    pv1 = *reinterpret_cast<const u16x8*>(Vh + kvbase + (size_t)(key0 + kp * 2 + 2) * DH + d0);
  };
  auto load_b = [&](int key0) -> f32x4 {
    f32x4 r;
#pragma unroll
    for (int n = 0; n < 4; ++n) r[n] = biasL[bbase + key0 + n * 16 + c];
    return r;
  };
  auto write_v = [&](unsigned short* VTdst) {
#pragma unroll
    for (int j = 0; j < 8; ++j) {
      int d = d0 + j;  // d&7 == j
      unsigned int pk = (unsigned int)pv0[j] | ((unsigned int)pv1[j] << 16);
      int byte = (d * 128 + kp * 4) ^ ((j ^ ((d >> 3) & 7)) << 4);
      *(unsigned int*)((char*)VTdst + byte) = pk;
    }
  };

  auto compute_tile = [&](const unsigned short* Kc, const unsigned short* Vc, f32x4 bR) {
    // QK^T both frags: s[f][n] init = bias (C-in); C/D row=g*4+j, col=c
    f32x4 s[2][4];
    __builtin_amdgcn_s_setprio(1);
#pragma unroll
    for (int n = 0; n < 4; ++n) {
      f32x4 bi = {bR[n], bR[n], bR[n], bR[n]};
      s[0][n] = bi; s[1][n] = bi;
#pragma unroll
      for (int t = 0; t < 2; ++t) {
        int row = n * 16 + c;
        int byte = (row * 128 + t * 64 + g * 16) ^ ((row & 7) << 4);
        bf16x8 kb = *reinterpret_cast<const bf16x8*>((const char*)Kc + byte);
        s[0][n] = mfma_bf16(qf[0][t], kb, s[0][n]);
        s[1][n] = mfma_bf16(qf[1][t], kb, s[1][n]);
      }
    }
    __builtin_amdgcn_s_setprio(0);

    // softmax per frag (exp2), P round-trip through per-wave LDS; pa to regs
    unsigned short* Pw = P_lds[w];
    bf16x8 pa[2][2];
#pragma unroll
    for (int f = 0; f < 2; ++f) {
#pragma unroll
      for (int n = 0; n < 4; ++n)
#pragma unroll
        for (int j = 0; j < 4; ++j) {
          float p = __builtin_amdgcn_exp2f(s[f][n][j]);
          lpart[f][j] += p;
          int row = g * 4 + j;
          int byte = (row * 128 + (n * 16 + c) * 2) ^ ((row & 7) << 4);
          *(__bf16*)((char*)Pw + byte) = (__bf16)p;
        }
#pragma unroll
      for (int t = 0; t < 2; ++t) {
        int byte = (c * 128 + t * 64 + g * 16) ^ ((c & 7) << 4);
        pa[f][t] = *reinterpret_cast<const bf16x8*>((char*)Pw + byte);
      }
    }

    // PV both frags: VT frag shared
    __builtin_amdgcn_s_setprio(1);
#pragma unroll
    for (int n = 0; n < 4; ++n) {
#pragma unroll
      for (int t = 0; t < 2; ++t) {
        int rv = n * 16 + c;
        int byte = (rv * 128 + t * 64 + g * 16) ^ (((rv & 7) ^ ((rv >> 3) & 7)) << 4);
        bf16x8 vb = *reinterpret_cast<const bf16x8*>((const char*)Vc + byte);
        o[0][n] = mfma_bf16(pa[0][t], vb, o[0][n]);
        o[1][n] = mfma_bf16(pa[1][t], vb, o[1][n]);
      }
    }
    __builtin_amdgcn_s_setprio(0);
  };

  // ---- prologue: stage tile 0 into buffer 0; bias for tile 0
  stage_k(0, K_lds[0]);
  load_v(0);
  f32x4 bA = load_b(0), bB;
  write_v(VT[0]);
  __syncthreads();

  // ---- main loop, 2 tiles per iteration (static buffer indices)
  for (int kt = 0; kt < 32; kt += 2) {
    stage_k((kt + 1) * 64, K_lds[1]);
    load_v((kt + 1) * 64);
    bB = load_b((kt + 1) * 64);
    compute_tile(K_lds[0], VT[0], bA);
    write_v(VT[1]);
    __syncthreads();

    if (kt + 2 < 32) {
      stage_k((kt + 2) * 64, K_lds[0]);
      load_v((kt + 2) * 64);
      bA = load_b((kt + 2) * 64);
    }
    compute_tile(K_lds[1], VT[1], bB);
    if (kt + 2 < 32) write_v(VT[0]);
    __syncthreads();
  }

  // reduce l across the 16-lane group (rows replicated across c)
#pragma unroll
  for (int mask = 1; mask < 16; mask <<= 1)
#pragma unroll
    for (int f = 0; f < 2; ++f)
#pragma unroll
      for (int j = 0; j < 4; ++j)
        lpart[f][j] += __shfl_xor(lpart[f][j], mask, 64);

  // epilogue: x = O / l, write merged-head layout [B*S, D]
#pragma unroll
  for (int f = 0; f < 2; ++f)
#pragma unroll
    for (int j = 0; j < 4; ++j) {
      float inv = 1.f / (l_sink[f][j] + lpart[f][j]);
      int q = q0 + f * 16 + g * 4 + j;
      size_t base = (bbase + q) * DD + h * DH + c;
#pragma unroll
      for (int n = 0; n < 4; ++n) {
        __bf16 hv = (__bf16)(o[f][n][j] * inv);
        Xbf[base + n * 16] = __builtin_bit_cast(unsigned short, hv);
      }
    }
}

// ---------------- launch ----------------
extern "C" void kernel_launch(void* const* d_in, const int* in_sizes, int n_in,
                              void* d_out, int out_size, void* d_ws, size_t ws_size,
                              hipStream_t stream) {
  const float* query = (const float*)d_in[0];
  const float* bias  = (const float*)d_in[1];
  const float* Wq = (const float*)d_in[2];
  const float* bq = (const float*)d_in[3];
  const float* Wk = (const float*)d_in[4];
  const float* bk = (const float*)d_in[5];
  const float* Wv = (const float*)d_in[6];
  const float* bv = (const float*)d_in[7];
  const float* Wo = (const float*)d_in[8];
  const float* bo = (const float*)d_in[9];
  const float* lk = (const float*)d_in[10];
  const float* lv = (const float*)d_in[11];

  char* ws = (char*)d_ws;
  unsigned short* Wqkv = (unsigned short*)(ws);                   //  6,291,456 B
  unsigned short* Wob  = (unsigned short*)(ws + 6291456);         //  2,097,152 B
  unsigned short* Qbf  = (unsigned short*)(ws + 8388608);         // 16,777,216 B
  unsigned short* Qh   = (unsigned short*)(ws + 25165824);        // 16,777,216 B
  unsigned short* Kh   = (unsigned short*)(ws + 41943040);        // 16,785,408 B
  unsigned short* Vh   = (unsigned short*)(ws + 58728448);        // 16,785,408 B
  float* biasL         = (float*)(ws + 75513856);                 //     32,768 B
  unsigned short* Xbf  = Qbf;  // Qbf dead after k_gemm_qkv; alias. total ~72 MiB
  float* out = (float*)d_out;

  k_prologue<<<12304, 256, 0, stream>>>(query, Wq, Wk, Wv, Wo, lk, lv, bias,
                                        Qbf, Wqkv, Wob, Kh, Vh, biasL);
  k_gemm_qkv<<<1536, 256, 0, stream>>>(Qbf, Wqkv, bq, bk, bv, Qh, Kh, Vh);
  k_attn<<<1024, 256, 0, stream>>>(Qh, Kh, Vh, biasL, Xbf);
  k_gemm_out<<<512, 256, 0, stream>>>(Xbf, Wob, bo, out);
}

// Round 8
// 325.781 us; speedup vs baseline: 2.4172x; 2.4172x over previous
//
#include <hip/hip_runtime.h>
#include <cstdint>
#include <cstddef>

#define DEV static __device__ __forceinline__

typedef __attribute__((ext_vector_type(8))) __bf16 bf16x8;
typedef __attribute__((ext_vector_type(8))) unsigned short u16x8;
typedef __attribute__((ext_vector_type(4))) float f32x4;

#define BB 4
#define SS 2048
#define DD 1024
#define HH 16
#define DH 64
#define SK 2049  // S+1 with sink token at position 0
#define LOG2E 1.4426950408889634f

DEV unsigned short f2bf(float f) {
  unsigned int u = __builtin_bit_cast(unsigned int, f);
  u += 0x7fffu + ((u >> 16) & 1u);  // RNE
  return (unsigned short)(u >> 16);
}
DEV float bf2f(unsigned short h) {
  unsigned int u = ((unsigned int)h) << 16;
  return __builtin_bit_cast(float, u);
}

DEV void gl_lds16(const void* g, void* l) {
  // async global->LDS, 16B per lane; LDS dest = wave-uniform base + lane*16
  __builtin_amdgcn_global_load_lds(
      (const __attribute__((address_space(1))) void*)g,
      (__attribute__((address_space(3))) void*)l, 16, 0, 0);
}

DEV f32x4 mfma_bf16(bf16x8 a, bf16x8 b, f32x4 c) {
  return __builtin_amdgcn_mfma_f32_16x16x32_bf16(a, b, c, 0, 0, 0);
}

// ---------------- fused prologue: converts + sink + bias prescale ----------------
// blocks [0,8192): query fp32->bf16 (4 elems/thread)
// blocks [8192,12288): W{q,k,v,o} fp32->bf16 into Wqkv / Wo
// blocks [12288,12304): sink K/V rows + bias*log2e
__global__ __launch_bounds__(256) void k_prologue(const float* __restrict__ query,
                                                  const float* __restrict__ w0,
                                                  const float* __restrict__ w1,
                                                  const float* __restrict__ w2,
                                                  const float* __restrict__ w3,
                                                  const float* __restrict__ lk,
                                                  const float* __restrict__ lv,
                                                  const float* __restrict__ bias,
                                                  unsigned short* __restrict__ Qbf,
                                                  unsigned short* __restrict__ wqkv,
                                                  unsigned short* __restrict__ wo,
                                                  unsigned short* __restrict__ Kh,
                                                  unsigned short* __restrict__ Vh,
                                                  float* __restrict__ biasL) {
  const int bid = blockIdx.x, tid = threadIdx.x;
  if (bid < 8192) {
    int i = bid * 256 + tid;
    float4 v = reinterpret_cast<const float4*>(query)[i];
    ushort4 o;
    o.x = f2bf(v.x); o.y = f2bf(v.y); o.z = f2bf(v.z); o.w = f2bf(v.w);
    reinterpret_cast<ushort4*>(Qbf)[i] = o;
  } else if (bid < 12288) {
    int i = (bid - 8192) * 256 + tid;
    int e = i * 4;                 // element index in 4x(1024*1024) space
    int sec = e >> 20;             // 0=Wq 1=Wk 2=Wv 3=Wo
    int off = e & 1048575;
    const float* s = (sec == 0) ? w0 : (sec == 1) ? w1 : (sec == 2) ? w2 : w3;
    float4 v = *reinterpret_cast<const float4*>(s + off);
    ushort4 o;
    o.x = f2bf(v.x); o.y = f2bf(v.y); o.z = f2bf(v.z); o.w = f2bf(v.w);
    unsigned short* d = (sec < 3) ? (wqkv + (size_t)sec * 1048576 + off) : (wo + off);
    *reinterpret_cast<ushort4*>(d) = o;
  } else {
    int t = (bid - 12288) * 256 + tid;  // 4096 = B*H*64
    int bh = t >> 6, d = t & 63;
    int h = bh & (HH - 1);
    Kh[(size_t)bh * SK * DH + d] = f2bf(lk[h * DH + d]);
    Vh[(size_t)bh * SK * DH + d] = f2bf(lv[h * DH + d]);
    biasL[t] = bias[t] * LOG2E;
    biasL[t + 4096] = bias[t + 4096] * LOG2E;
  }
}

// ---------------- GEMM (m97 structure): C[m,n] = sum_k A[m,k]*Bw[n,k] ----------------
// A:[M,1024] bf16, Bw:[N,1024] bf16 (B^T form). 128x128 tile, BK=32, 4 waves.
// 1-D grid with XCD-aware swizzle (T1): each XCD gets an m-major contiguous chunk.

__global__ __launch_bounds__(256) void k_gemm_qkv(const unsigned short* __restrict__ A,
                                                  const unsigned short* __restrict__ Bw,
                                                  const float* __restrict__ bq,
                                                  const float* __restrict__ bk,
                                                  const float* __restrict__ bv,
                                                  unsigned short* __restrict__ Qh,
                                                  unsigned short* __restrict__ Kh,
                                                  unsigned short* __restrict__ Vh) {
  __shared__ unsigned short As[128 * 32];
  __shared__ unsigned short Bs[128 * 32];
  const int tid = threadIdx.x, lane = tid & 63, wid = tid >> 6;
  const int g = lane >> 4, l15 = lane & 15;
  // XCD swizzle: 1536 blocks, 192/XCD, m-major (A-panel L2-resident)
  const int id = blockIdx.x;
  const int wk = (id & 7) * 192 + (id >> 3);
  const int m0 = (wk / 24) * 128, n0 = (wk % 24) * 128;
  const int wr = (wid >> 1) * 64, wc = (wid & 1) * 64;

  f32x4 acc[4][4] = {};

  for (int k0 = 0; k0 < 1024; k0 += 32) {
    __syncthreads();
#pragma unroll
    for (int i = 0; i < 2; ++i) {
      int e = i * 2048 + wid * 512 + lane * 8;
      int r = e >> 5, c = e & 31;
      gl_lds16(A + (size_t)(m0 + r) * 1024 + k0 + c, &As[i * 2048 + wid * 512]);
      gl_lds16(Bw + (size_t)(n0 + r) * 1024 + k0 + c, &Bs[i * 2048 + wid * 512]);
    }
    __syncthreads();  // drains vmcnt before barrier
    bf16x8 af[4], bf[4];
#pragma unroll
    for (int m = 0; m < 4; ++m)
      af[m] = *reinterpret_cast<const bf16x8*>(&As[(wr + m * 16 + l15) * 32 + g * 8]);
#pragma unroll
    for (int n = 0; n < 4; ++n)
      bf[n] = *reinterpret_cast<const bf16x8*>(&Bs[(wc + n * 16 + l15) * 32 + g * 8]);
#pragma unroll
    for (int m = 0; m < 4; ++m)
#pragma unroll
      for (int n = 0; n < 4; ++n)
        acc[m][n] = mfma_bf16(af[m], bf[n], acc[m][n]);
  }

  // epilogue: scatter into per-head Q/K/V, fold biases + q-scale, K/V at key+1
  // Q additionally scaled by log2e so attention softmax can use exp2 directly.
#pragma unroll
  for (int n = 0; n < 4; ++n) {
    int gn = n0 + wc + n * 16 + l15;
    int sec = gn >> 10;           // block-uniform (128 | 1024)
    int nh = gn & 1023;
    int h = nh >> 6, d = nh & 63;
    const float* bias = (sec == 0) ? bq : (sec == 1) ? bk : bv;
    float bia = bias[nh];
#pragma unroll
    for (int m = 0; m < 4; ++m) {
#pragma unroll
      for (int j = 0; j < 4; ++j) {
        int row = m0 + wr + m * 16 + g * 4 + j;
        int b = row >> 11, s = row & 2047;
        float v = acc[m][n][j] + bia;
        if (sec == 0) {
          Qh[((size_t)(b * HH + h) * SS + s) * DH + d] = f2bf(v * (0.125f * LOG2E));
        } else if (sec == 1) {
          Kh[((size_t)(b * HH + h) * SK + s + 1) * DH + d] = f2bf(v);
        } else {
          Vh[((size_t)(b * HH + h) * SK + s + 1) * DH + d] = f2bf(v);
        }
      }
    }
  }
}

__global__ __launch_bounds__(256) void k_gemm_out(const unsigned short* __restrict__ A,
                                                  const unsigned short* __restrict__ Bw,
                                                  const float* __restrict__ bo,
                                                  float* __restrict__ out) {
  __shared__ unsigned short As[128 * 32];
  __shared__ unsigned short Bs[128 * 32];
  const int tid = threadIdx.x, lane = tid & 63, wid = tid >> 6;
  const int g = lane >> 4, l15 = lane & 15;
  // XCD swizzle: 512 blocks, 64/XCD, m-major (B fully L2-resident: 2MB)
  const int id = blockIdx.x;
  const int wk = (id & 7) * 64 + (id >> 3);
  const int m0 = (wk >> 3) * 128, n0 = (wk & 7) * 128;
  const int wr = (wid >> 1) * 64, wc = (wid & 1) * 64;

  f32x4 acc[4][4] = {};

  for (int k0 = 0; k0 < 1024; k0 += 32) {
    __syncthreads();
#pragma unroll
    for (int i = 0; i < 2; ++i) {
      int e = i * 2048 + wid * 512 + lane * 8;
      int r = e >> 5, c = e & 31;
      gl_lds16(A + (size_t)(m0 + r) * 1024 + k0 + c, &As[i * 2048 + wid * 512]);
      gl_lds16(Bw + (size_t)(n0 + r) * 1024 + k0 + c, &Bs[i * 2048 + wid * 512]);
    }
    __syncthreads();
    bf16x8 af[4], bf[4];
#pragma unroll
    for (int m = 0; m < 4; ++m)
      af[m] = *reinterpret_cast<const bf16x8*>(&As[(wr + m * 16 + l15) * 32 + g * 8]);
#pragma unroll
    for (int n = 0; n < 4; ++n)
      bf[n] = *reinterpret_cast<const bf16x8*>(&Bs[(wc + n * 16 + l15) * 32 + g * 8]);
#pragma unroll
    for (int m = 0; m < 4; ++m)
#pragma unroll
      for (int n = 0; n < 4; ++n)
        acc[m][n] = mfma_bf16(af[m], bf[n], acc[m][n]);
  }

#pragma unroll
  for (int n = 0; n < 4; ++n) {
    int gn = n0 + wc + n * 16 + l15;
    float bia = bo[gn];
#pragma unroll
    for (int m = 0; m < 4; ++m) {
#pragma unroll
      for (int j = 0; j < 4; ++j) {
        int row = m0 + wr + m * 16 + g * 4 + j;
        out[(size_t)row * 1024 + gn] = acc[m][n][j] + bia;
      }
    }
  }
}

// ---------------- flash attention with sink token ----------------
// Block: 4 waves; each wave owns 32 q-rows (2 fragments) -> block = 128 q.
// KV tile = 64 keys, double-buffered K/VT, one barrier per tile.
// Bias (pre-scaled by log2e) is prefetched a tile ahead and injected as the
// MFMA C-initializer (exact: softmax shift-invariance unaffected).
// XCD swizzle: 8 consecutive (b,h) per XCD -> KV working set 4MB = one L2.
// NOTE: no min-waves launch_bounds cap — round 6 showed (256,4) forces a
// catastrophic scratch spill (VGPR 124->64, 2.6 GB HBM traffic, 4x slower).
__global__ __launch_bounds__(256) void k_attn(const unsigned short* __restrict__ Qh,
                                              const unsigned short* __restrict__ Kh,
                                              const unsigned short* __restrict__ Vh,
                                              const float* __restrict__ biasL,
                                              unsigned short* __restrict__ Xbf) {
  __shared__ unsigned short K_lds[2][64 * 64];   // [key][d], rows XOR-swizzled (row&7)
  __shared__ unsigned short VT[2][64 * 64];      // [d][key], double-XOR swizzled
  __shared__ unsigned short P_lds[4][16 * 64];   // per-wave P (one frag at a time)

  const int tid = threadIdx.x, lane = tid & 63, w = tid >> 6;
  const int g = lane >> 4, c = lane & 15;
  const int idx = (blockIdx.x & 7) * 128 + (blockIdx.x >> 3);  // T1 swizzle, 1024 blocks
  const int bh = idx >> 4, qt = idx & 15;
  const int b = bh >> 4, h = bh & 15;
  const int q0 = qt * 128 + w * 32;
  const size_t kvbase = (size_t)bh * SK * DH;
  const size_t bbase = (size_t)b * SS;

  // Q fragments for both 16-row halves (row = c, d = 32t + 8g + j)
  bf16x8 qf[2][2];
#pragma unroll
  for (int f = 0; f < 2; ++f)
#pragma unroll
    for (int t = 0; t < 2; ++t)
      qf[f][t] = *reinterpret_cast<const bf16x8*>(
          Qh + ((size_t)bh * SS + q0 + f * 16) * DH + (size_t)c * DH + t * 32 + g * 8);

  // sink: s0[f][j] = q_row . k_sink (bias col for sink is 0); exp2 domain.
  // l_sink is folded into lpart via a c==0 seed (16-lane reduce at the end
  // then counts it exactly once) so its live range ends here (-8 VGPR).
  bf16x8 kb_sink[2];
#pragma unroll
  for (int t = 0; t < 2; ++t)
    kb_sink[t] = *reinterpret_cast<const bf16x8*>(Kh + kvbase + t * 32 + g * 8);
  float lpart[2][4];
  f32x4 o[2][4];
#pragma unroll
  for (int f = 0; f < 2; ++f) {
    f32x4 s0 = {0.f, 0.f, 0.f, 0.f};
#pragma unroll
    for (int t = 0; t < 2; ++t) s0 = mfma_bf16(qf[f][t], kb_sink[t], s0);
#pragma unroll
    for (int j = 0; j < 4; ++j) {
      float ls = __builtin_amdgcn_exp2f(s0[j]);
      lpart[f][j] = (c == 0) ? ls : 0.f;
#pragma unroll
      for (int n = 0; n < 4; ++n) {
        float v = bf2f(Vh[kvbase + n * 16 + c]);
        o[f][n][j] = ls * v;
      }
    }
  }

  // V prefetch state: thread owns k-rows {2kp, 2kp+1}, d-slice d0..d0+7
  const int kp = tid >> 3;          // 0..31
  const int d0 = (tid & 7) * 8;
  u16x8 pv0, pv1;

  auto stage_k = [&](int key0, unsigned short* Kdst) {
#pragma unroll
    for (int i = 0; i < 2; ++i) {
      int ob = i * 4096 + w * 1024 + lane * 16;  // dest tile byte
      int r = ob >> 7, cb = ob & 127;
      int sc = cb ^ ((r & 7) << 4);
      gl_lds16(Kh + kvbase + (size_t)(key0 + r + 1) * DH + (sc >> 1),
               (char*)Kdst + i * 4096 + w * 1024);
    }
  };
  auto load_v = [&](int key0) {
    pv0 = *reinterpret_cast<const u16x8*>(Vh + kvbase + (size_t)(key0 + kp * 2 + 1) * DH + d0);
    pv1 = *reinterpret_cast<const u16x8*>(Vh + kvbase + (size_t)(key0 + kp * 2 + 2) * DH + d0);
  };
  auto load_b = [&](int key0) -> f32x4 {
    f32x4 r;
#pragma unroll
    for (int n = 0; n < 4; ++n) r[n] = biasL[bbase + key0 + n * 16 + c];
    return r;
  };
  auto write_v = [&](unsigned short* VTdst) {
#pragma unroll
    for (int j = 0; j < 8; ++j) {
      int d = d0 + j;  // d&7 == j
      unsigned int pk = (unsigned int)pv0[j] | ((unsigned int)pv1[j] << 16);
      int byte = (d * 128 + kp * 4) ^ ((j ^ ((d >> 3) & 7)) << 4);
      *(unsigned int*)((char*)VTdst + byte) = pk;
    }
  };

  auto compute_tile = [&](const unsigned short* Kc, const unsigned short* Vc, f32x4 bR) {
    // QK^T both frags: s[f][n] init = bias (C-in); C/D row=g*4+j, col=c
    f32x4 s[2][4];
    __builtin_amdgcn_s_setprio(1);
#pragma unroll
    for (int n = 0; n < 4; ++n) {
      f32x4 bi = {bR[n], bR[n], bR[n], bR[n]};
      s[0][n] = bi; s[1][n] = bi;
#pragma unroll
      for (int t = 0; t < 2; ++t) {
        int row = n * 16 + c;
        int byte = (row * 128 + t * 64 + g * 16) ^ ((row & 7) << 4);
        bf16x8 kb = *reinterpret_cast<const bf16x8*>((const char*)Kc + byte);
        s[0][n] = mfma_bf16(qf[0][t], kb, s[0][n]);
        s[1][n] = mfma_bf16(qf[1][t], kb, s[1][n]);
      }
    }
    __builtin_amdgcn_s_setprio(0);

    // softmax per frag (exp2), P round-trip through per-wave LDS; pa to regs
    unsigned short* Pw = P_lds[w];
    bf16x8 pa[2][2];
#pragma unroll
    for (int f = 0; f < 2; ++f) {
#pragma unroll
      for (int n = 0; n < 4; ++n)
#pragma unroll
        for (int j = 0; j < 4; ++j) {
          float p = __builtin_amdgcn_exp2f(s[f][n][j]);
          lpart[f][j] += p;
          int row = g * 4 + j;
          int byte = (row * 128 + (n * 16 + c) * 2) ^ ((row & 7) << 4);
          *(__bf16*)((char*)Pw + byte) = (__bf16)p;
        }
#pragma unroll
      for (int t = 0; t < 2; ++t) {
        int byte = (c * 128 + t * 64 + g * 16) ^ ((c & 7) << 4);
        pa[f][t] = *reinterpret_cast<const bf16x8*>((char*)Pw + byte);
      }
    }

    // PV both frags: VT frag shared
    __builtin_amdgcn_s_setprio(1);
#pragma unroll
    for (int n = 0; n < 4; ++n) {
#pragma unroll
      for (int t = 0; t < 2; ++t) {
        int rv = n * 16 + c;
        int byte = (rv * 128 + t * 64 + g * 16) ^ (((rv & 7) ^ ((rv >> 3) & 7)) << 4);
        bf16x8 vb = *reinterpret_cast<const bf16x8*>((const char*)Vc + byte);
        o[0][n] = mfma_bf16(pa[0][t], vb, o[0][n]);
        o[1][n] = mfma_bf16(pa[1][t], vb, o[1][n]);
      }
    }
    __builtin_amdgcn_s_setprio(0);
  };

  // ---- prologue: stage tile 0 into buffer 0; bias for tile 0
  stage_k(0, K_lds[0]);
  load_v(0);
  f32x4 bA = load_b(0), bB;
  write_v(VT[0]);
  __syncthreads();

  // ---- main loop, 2 tiles per iteration (static buffer indices)
  for (int kt = 0; kt < 32; kt += 2) {
    stage_k((kt + 1) * 64, K_lds[1]);
    load_v((kt + 1) * 64);
    bB = load_b((kt + 1) * 64);
    compute_tile(K_lds[0], VT[0], bA);
    write_v(VT[1]);
    __syncthreads();

    if (kt + 2 < 32) {
      stage_k((kt + 2) * 64, K_lds[0]);
      load_v((kt + 2) * 64);
      bA = load_b((kt + 2) * 64);
    }
    compute_tile(K_lds[1], VT[1], bB);
    if (kt + 2 < 32) write_v(VT[0]);
    __syncthreads();
  }

  // reduce l across the 16-lane group (rows replicated across c; includes
  // the sink seed from lane c==0)
#pragma unroll
  for (int mask = 1; mask < 16; mask <<= 1)
#pragma unroll
    for (int f = 0; f < 2; ++f)
#pragma unroll
      for (int j = 0; j < 4; ++j)
        lpart[f][j] += __shfl_xor(lpart[f][j], mask, 64);

  // epilogue: x = O / l, write merged-head layout [B*S, D]
#pragma unroll
  for (int f = 0; f < 2; ++f)
#pragma unroll
    for (int j = 0; j < 4; ++j) {
      float inv = 1.f / lpart[f][j];
      int q = q0 + f * 16 + g * 4 + j;
      size_t base = (bbase + q) * DD + h * DH + c;
#pragma unroll
      for (int n = 0; n < 4; ++n) {
        __bf16 hv = (__bf16)(o[f][n][j] * inv);
        Xbf[base + n * 16] = __builtin_bit_cast(unsigned short, hv);
      }
    }
}

// ---------------- launch ----------------
extern "C" void kernel_launch(void* const* d_in, const int* in_sizes, int n_in,
                              void* d_out, int out_size, void* d_ws, size_t ws_size,
                              hipStream_t stream) {
  const float* query = (const float*)d_in[0];
  const float* bias  = (const float*)d_in[1];
  const float* Wq = (const float*)d_in[2];
  const float* bq = (const float*)d_in[3];
  const float* Wk = (const float*)d_in[4];
  const float* bk = (const float*)d_in[5];
  const float* Wv = (const float*)d_in[6];
  const float* bv = (const float*)d_in[7];
  const float* Wo = (const float*)d_in[8];
  const float* bo = (const float*)d_in[9];
  const float* lk = (const float*)d_in[10];
  const float* lv = (const float*)d_in[11];

  char* ws = (char*)d_ws;
  unsigned short* Wqkv = (unsigned short*)(ws);                   //  6,291,456 B
  unsigned short* Wob  = (unsigned short*)(ws + 6291456);         //  2,097,152 B
  unsigned short* Qbf  = (unsigned short*)(ws + 8388608);         // 16,777,216 B
  unsigned short* Qh   = (unsigned short*)(ws + 25165824);        // 16,777,216 B
  unsigned short* Kh   = (unsigned short*)(ws + 41943040);        // 16,785,408 B
  unsigned short* Vh   = (unsigned short*)(ws + 58728448);        // 16,785,408 B
  float* biasL         = (float*)(ws + 75513856);                 //     32,768 B
  unsigned short* Xbf  = Qbf;  // Qbf dead after k_gemm_qkv; alias. total ~72 MiB
  float* out = (float*)d_out;

  k_prologue<<<12304, 256, 0, stream>>>(query, Wq, Wk, Wv, Wo, lk, lv, bias,
                                        Qbf, Wqkv, Wob, Kh, Vh, biasL);
  k_gemm_qkv<<<1536, 256, 0, stream>>>(Qbf, Wqkv, bq, bk, bv, Qh, Kh, Vh);
  k_attn<<<1024, 256, 0, stream>>>(Qh, Kh, Vh, biasL, Xbf);
  k_gemm_out<<<512, 256, 0, stream>>>(Xbf, Wob, bo, out);
}

// Round 11
// 322.187 us; speedup vs baseline: 2.4442x; 1.0112x over previous
//
#include <hip/hip_runtime.h>
#include <cstdint>
#include <cstddef>

#define DEV static __device__ __forceinline__

typedef __attribute__((ext_vector_type(8))) __bf16 bf16x8;
typedef __attribute__((ext_vector_type(8))) unsigned short u16x8;
typedef __attribute__((ext_vector_type(4))) float f32x4;

#define BB 4
#define SS 2048
#define DD 1024
#define HH 16
#define DH 64
#define SK 2049  // S+1 with sink token at position 0
#define LOG2E 1.4426950408889634f

DEV unsigned short f2bf(float f) {
  unsigned int u = __builtin_bit_cast(unsigned int, f);
  u += 0x7fffu + ((u >> 16) & 1u);  // RNE
  return (unsigned short)(u >> 16);
}
DEV float bf2f(unsigned short h) {
  unsigned int u = ((unsigned int)h) << 16;
  return __builtin_bit_cast(float, u);
}

DEV void gl_lds16(const void* g, void* l) {
  // async global->LDS, 16B per lane; LDS dest = wave-uniform base + lane*16
  __builtin_amdgcn_global_load_lds(
      (const __attribute__((address_space(1))) void*)g,
      (__attribute__((address_space(3))) void*)l, 16, 0, 0);
}

DEV f32x4 mfma_bf16(bf16x8 a, bf16x8 b, f32x4 c) {
  return __builtin_amdgcn_mfma_f32_16x16x32_bf16(a, b, c, 0, 0, 0);
}

// ---------------- fused prologue: converts + sink + bias prescale ----------------
// blocks [0,8192): query fp32->bf16 (4 elems/thread)
// blocks [8192,12288): W{q,k,v,o} fp32->bf16 into Wqkv / Wo
// blocks [12288,12304): sink K/V rows + bias*log2e
__global__ __launch_bounds__(256) void k_prologue(const float* __restrict__ query,
                                                  const float* __restrict__ w0,
                                                  const float* __restrict__ w1,
                                                  const float* __restrict__ w2,
                                                  const float* __restrict__ w3,
                                                  const float* __restrict__ lk,
                                                  const float* __restrict__ lv,
                                                  const float* __restrict__ bias,
                                                  unsigned short* __restrict__ Qbf,
                                                  unsigned short* __restrict__ wqkv,
                                                  unsigned short* __restrict__ wo,
                                                  unsigned short* __restrict__ Kh,
                                                  unsigned short* __restrict__ Vh,
                                                  float* __restrict__ biasL) {
  const int bid = blockIdx.x, tid = threadIdx.x;
  if (bid < 8192) {
    int i = bid * 256 + tid;
    float4 v = reinterpret_cast<const float4*>(query)[i];
    ushort4 o;
    o.x = f2bf(v.x); o.y = f2bf(v.y); o.z = f2bf(v.z); o.w = f2bf(v.w);
    reinterpret_cast<ushort4*>(Qbf)[i] = o;
  } else if (bid < 12288) {
    int i = (bid - 8192) * 256 + tid;
    int e = i * 4;                 // element index in 4x(1024*1024) space
    int sec = e >> 20;             // 0=Wq 1=Wk 2=Wv 3=Wo
    int off = e & 1048575;
    const float* s = (sec == 0) ? w0 : (sec == 1) ? w1 : (sec == 2) ? w2 : w3;
    float4 v = *reinterpret_cast<const float4*>(s + off);
    ushort4 o;
    o.x = f2bf(v.x); o.y = f2bf(v.y); o.z = f2bf(v.z); o.w = f2bf(v.w);
    unsigned short* d = (sec < 3) ? (wqkv + (size_t)sec * 1048576 + off) : (wo + off);
    *reinterpret_cast<ushort4*>(d) = o;
  } else {
    int t = (bid - 12288) * 256 + tid;  // 4096 = B*H*64
    int bh = t >> 6, d = t & 63;
    int h = bh & (HH - 1);
    Kh[(size_t)bh * SK * DH + d] = f2bf(lk[h * DH + d]);
    Vh[(size_t)bh * SK * DH + d] = f2bf(lv[h * DH + d]);
    biasL[t] = bias[t] * LOG2E;
    biasL[t + 4096] = bias[t + 4096] * LOG2E;
  }
}

// ---------------- GEMM (m97 structure): C[m,n] = sum_k A[m,k]*Bw[n,k] ----------------
// A:[M,1024] bf16, Bw:[N,1024] bf16 (B^T form). 128x128 tile, BK=32, 4 waves.
// 1-D grid with XCD-aware swizzle (T1): each XCD gets an m-major contiguous chunk.

__global__ __launch_bounds__(256) void k_gemm_qkv(const unsigned short* __restrict__ A,
                                                  const unsigned short* __restrict__ Bw,
                                                  const float* __restrict__ bq,
                                                  const float* __restrict__ bk,
                                                  const float* __restrict__ bv,
                                                  unsigned short* __restrict__ Qh,
                                                  unsigned short* __restrict__ Kh,
                                                  unsigned short* __restrict__ Vh) {
  __shared__ unsigned short As[128 * 32];
  __shared__ unsigned short Bs[128 * 32];
  const int tid = threadIdx.x, lane = tid & 63, wid = tid >> 6;
  const int g = lane >> 4, l15 = lane & 15;
  // XCD swizzle: 1536 blocks, 192/XCD, m-major (A-panel L2-resident)
  const int id = blockIdx.x;
  const int wk = (id & 7) * 192 + (id >> 3);
  const int m0 = (wk / 24) * 128, n0 = (wk % 24) * 128;
  const int wr = (wid >> 1) * 64, wc = (wid & 1) * 64;

  f32x4 acc[4][4] = {};

  for (int k0 = 0; k0 < 1024; k0 += 32) {
    __syncthreads();
#pragma unroll
    for (int i = 0; i < 2; ++i) {
      int e = i * 2048 + wid * 512 + lane * 8;
      int r = e >> 5, c = e & 31;
      gl_lds16(A + (size_t)(m0 + r) * 1024 + k0 + c, &As[i * 2048 + wid * 512]);
      gl_lds16(Bw + (size_t)(n0 + r) * 1024 + k0 + c, &Bs[i * 2048 + wid * 512]);
    }
    __syncthreads();  // drains vmcnt before barrier
    bf16x8 af[4], bf[4];
#pragma unroll
    for (int m = 0; m < 4; ++m)
      af[m] = *reinterpret_cast<const bf16x8*>(&As[(wr + m * 16 + l15) * 32 + g * 8]);
#pragma unroll
    for (int n = 0; n < 4; ++n)
      bf[n] = *reinterpret_cast<const bf16x8*>(&Bs[(wc + n * 16 + l15) * 32 + g * 8]);
#pragma unroll
    for (int m = 0; m < 4; ++m)
#pragma unroll
      for (int n = 0; n < 4; ++n)
        acc[m][n] = mfma_bf16(af[m], bf[n], acc[m][n]);
  }

  // epilogue: scatter into per-head Q/K/V, fold biases + q-scale, K/V at key+1
  // Q additionally scaled by log2e so attention softmax can use exp2 directly.
#pragma unroll
  for (int n = 0; n < 4; ++n) {
    int gn = n0 + wc + n * 16 + l15;
    int sec = gn >> 10;           // block-uniform (128 | 1024)
    int nh = gn & 1023;
    int h = nh >> 6, d = nh & 63;
    const float* bias = (sec == 0) ? bq : (sec == 1) ? bk : bv;
    float bia = bias[nh];
#pragma unroll
    for (int m = 0; m < 4; ++m) {
#pragma unroll
      for (int j = 0; j < 4; ++j) {
        int row = m0 + wr + m * 16 + g * 4 + j;
        int b = row >> 11, s = row & 2047;
        float v = acc[m][n][j] + bia;
        if (sec == 0) {
          Qh[((size_t)(b * HH + h) * SS + s) * DH + d] = f2bf(v * (0.125f * LOG2E));
        } else if (sec == 1) {
          Kh[((size_t)(b * HH + h) * SK + s + 1) * DH + d] = f2bf(v);
        } else {
          Vh[((size_t)(b * HH + h) * SK + s + 1) * DH + d] = f2bf(v);
        }
      }
    }
  }
}

__global__ __launch_bounds__(256) void k_gemm_out(const unsigned short* __restrict__ A,
                                                  const unsigned short* __restrict__ Bw,
                                                  const float* __restrict__ bo,
                                                  float* __restrict__ out) {
  __shared__ unsigned short As[128 * 32];
  __shared__ unsigned short Bs[128 * 32];
  const int tid = threadIdx.x, lane = tid & 63, wid = tid >> 6;
  const int g = lane >> 4, l15 = lane & 15;
  // XCD swizzle: 512 blocks, 64/XCD, m-major (B fully L2-resident: 2MB)
  const int id = blockIdx.x;
  const int wk = (id & 7) * 64 + (id >> 3);
  const int m0 = (wk >> 3) * 128, n0 = (wk & 7) * 128;
  const int wr = (wid >> 1) * 64, wc = (wid & 1) * 64;

  f32x4 acc[4][4] = {};

  for (int k0 = 0; k0 < 1024; k0 += 32) {
    __syncthreads();
#pragma unroll
    for (int i = 0; i < 2; ++i) {
      int e = i * 2048 + wid * 512 + lane * 8;
      int r = e >> 5, c = e & 31;
      gl_lds16(A + (size_t)(m0 + r) * 1024 + k0 + c, &As[i * 2048 + wid * 512]);
      gl_lds16(Bw + (size_t)(n0 + r) * 1024 + k0 + c, &Bs[i * 2048 + wid * 512]);
    }
    __syncthreads();
    bf16x8 af[4], bf[4];
#pragma unroll
    for (int m = 0; m < 4; ++m)
      af[m] = *reinterpret_cast<const bf16x8*>(&As[(wr + m * 16 + l15) * 32 + g * 8]);
#pragma unroll
    for (int n = 0; n < 4; ++n)
      bf[n] = *reinterpret_cast<const bf16x8*>(&Bs[(wc + n * 16 + l15) * 32 + g * 8]);
#pragma unroll
    for (int m = 0; m < 4; ++m)
#pragma unroll
      for (int n = 0; n < 4; ++n)
        acc[m][n] = mfma_bf16(af[m], bf[n], acc[m][n]);
  }

#pragma unroll
  for (int n = 0; n < 4; ++n) {
    int gn = n0 + wc + n * 16 + l15;
    float bia = bo[gn];
#pragma unroll
    for (int m = 0; m < 4; ++m) {
#pragma unroll
      for (int j = 0; j < 4; ++j) {
        int row = m0 + wr + m * 16 + g * 4 + j;
        out[(size_t)row * 1024 + gn] = acc[m][n][j] + bia;
      }
    }
  }
}

// ---------------- flash attention with sink token ----------------
// Block: 4 waves; each wave owns 32 q-rows (2 fragments) -> block = 128 q.
// KV tile = 64 keys, double-buffered K/VT, one barrier per tile.
// Bias (pre-scaled by log2e) is prefetched a tile ahead and injected as the
// MFMA C-initializer (exact: softmax shift-invariance unaffected).
// Softmax denominator l computed by MFMA (P @ ones): row-sum replicated to
// every lane, accumulated in l_acc across tiles -- removes 32 VALU adds/tile
// and the end-of-kernel shuffle reduce (round 8: VALUBusy 40% >> MfmaUtil 23%).
// XCD swizzle: 8 consecutive (b,h) per XCD -> KV working set 4MB = one L2
// (round 8: FETCH 139.5 -> 24.7 MB).
// NOTE: no min-waves launch_bounds cap — round 6 showed (256,4) forces a
// catastrophic scratch spill (VGPR 124->64, 2.6 GB HBM traffic, 4x slower).
__global__ __launch_bounds__(256) void k_attn(const unsigned short* __restrict__ Qh,
                                              const unsigned short* __restrict__ Kh,
                                              const unsigned short* __restrict__ Vh,
                                              const float* __restrict__ biasL,
                                              unsigned short* __restrict__ Xbf) {
  __shared__ unsigned short K_lds[2][64 * 64];   // [key][d], rows XOR-swizzled (row&7)
  __shared__ unsigned short VT[2][64 * 64];      // [d][key], double-XOR swizzled
  __shared__ unsigned short P_lds[4][16 * 64];   // per-wave P (one frag at a time)

  const int tid = threadIdx.x, lane = tid & 63, w = tid >> 6;
  const int g = lane >> 4, c = lane & 15;
  const int idx = (blockIdx.x & 7) * 128 + (blockIdx.x >> 3);  // T1 swizzle, 1024 blocks
  const int bh = idx >> 4, qt = idx & 15;
  const int b = bh >> 4, h = bh & 15;
  const int q0 = qt * 128 + w * 32;
  const size_t kvbase = (size_t)bh * SK * DH;
  const size_t bbase = (size_t)b * SS;

  // Q fragments for both 16-row halves (row = c, d = 32t + 8g + j)
  bf16x8 qf[2][2];
#pragma unroll
  for (int f = 0; f < 2; ++f)
#pragma unroll
    for (int t = 0; t < 2; ++t)
      qf[f][t] = *reinterpret_cast<const bf16x8*>(
          Qh + ((size_t)bh * SS + q0 + f * 16) * DH + (size_t)c * DH + t * 32 + g * 8);

  // sink: s0[f][j] = q_row . k_sink (bias col for sink is 0); exp2 domain.
  // l_acc seeded with l_sink (replicated across lanes; MFMA l-sum keeps the
  // replication invariant so no final cross-lane reduce is needed).
  bf16x8 kb_sink[2];
#pragma unroll
  for (int t = 0; t < 2; ++t)
    kb_sink[t] = *reinterpret_cast<const bf16x8*>(Kh + kvbase + t * 32 + g * 8);
  f32x4 l_acc[2];
  f32x4 o[2][4];
#pragma unroll
  for (int f = 0; f < 2; ++f) {
    f32x4 s0 = {0.f, 0.f, 0.f, 0.f};
#pragma unroll
    for (int t = 0; t < 2; ++t) s0 = mfma_bf16(qf[f][t], kb_sink[t], s0);
#pragma unroll
    for (int j = 0; j < 4; ++j) {
      float ls = __builtin_amdgcn_exp2f(s0[j]);
      l_acc[f][j] = ls;
#pragma unroll
      for (int n = 0; n < 4; ++n) {
        float v = bf2f(Vh[kvbase + n * 16 + c]);
        o[f][n][j] = ls * v;
      }
    }
  }

  // V prefetch state: thread owns k-rows {2kp, 2kp+1}, d-slice d0..d0+7
  const int kp = tid >> 3;          // 0..31
  const int d0 = (tid & 7) * 8;
  u16x8 pv0, pv1;

  auto stage_k = [&](int key0, unsigned short* Kdst) {
#pragma unroll
    for (int i = 0; i < 2; ++i) {
      int ob = i * 4096 + w * 1024 + lane * 16;  // dest tile byte
      int r = ob >> 7, cb = ob & 127;
      int sc = cb ^ ((r & 7) << 4);
      gl_lds16(Kh + kvbase + (size_t)(key0 + r + 1) * DH + (sc >> 1),
               (char*)Kdst + i * 4096 + w * 1024);
    }
  };
  auto load_v = [&](int key0) {
    pv0 = *reinterpret_cast<const u16x8*>(Vh + kvbase + (size_t)(key0 + kp * 2 + 1) * DH + d0);
    pv1 = *reinterpret_cast<const u16x8*>(Vh + kvbase + (size_t)(key0 + kp * 2 + 2) * DH + d0);
  };
  auto load_b = [&](int key0) -> f32x4 {
    f32x4 r;
#pragma unroll
    for (int n = 0; n < 4; ++n) r[n] = biasL[bbase + key0 + n * 16 + c];
    return r;
  };
  auto write_v = [&](unsigned short* VTdst) {
#pragma unroll
    for (int j = 0; j < 8; ++j) {
      int d = d0 + j;  // d&7 == j
      unsigned int pk = (unsigned int)pv0[j] | ((unsigned int)pv1[j] << 16);
      int byte = (d * 128 + kp * 4) ^ ((j ^ ((d >> 3) & 7)) << 4);
      *(unsigned int*)((char*)VTdst + byte) = pk;
    }
  };

  auto compute_tile = [&](const unsigned short* Kc, const unsigned short* Vc, f32x4 bR) {
    // QK^T both frags: s[f][n] init = bias (C-in); C/D row=g*4+j, col=c
    f32x4 s[2][4];
    __builtin_amdgcn_s_setprio(1);
#pragma unroll
    for (int n = 0; n < 4; ++n) {
      f32x4 bi = {bR[n], bR[n], bR[n], bR[n]};
      s[0][n] = bi; s[1][n] = bi;
#pragma unroll
      for (int t = 0; t < 2; ++t) {
        int row = n * 16 + c;
        int byte = (row * 128 + t * 64 + g * 16) ^ ((row & 7) << 4);
        bf16x8 kb = *reinterpret_cast<const bf16x8*>((const char*)Kc + byte);
        s[0][n] = mfma_bf16(qf[0][t], kb, s[0][n]);
        s[1][n] = mfma_bf16(qf[1][t], kb, s[1][n]);
      }
    }
    __builtin_amdgcn_s_setprio(0);

    // softmax per frag (exp2), P round-trip through per-wave LDS; pa to regs
    unsigned short* Pw = P_lds[w];
    bf16x8 pa[2][2];
#pragma unroll
    for (int f = 0; f < 2; ++f) {
#pragma unroll
      for (int n = 0; n < 4; ++n)
#pragma unroll
        for (int j = 0; j < 4; ++j) {
          float p = __builtin_amdgcn_exp2f(s[f][n][j]);
          int row = g * 4 + j;
          int byte = (row * 128 + (n * 16 + c) * 2) ^ ((row & 7) << 4);
          *(__bf16*)((char*)Pw + byte) = (__bf16)p;
        }
#pragma unroll
      for (int t = 0; t < 2; ++t) {
        int byte = (c * 128 + t * 64 + g * 16) ^ ((c & 7) << 4);
        pa[f][t] = *reinterpret_cast<const bf16x8*>((char*)Pw + byte);
      }
    }

    // l-sum via MFMA: l_acc[f] += P @ ones (row-sum replicated to all cols).
    // ones built here (s[][] is dead -> no pressure at the VGPR=128 cliff).
    bf16x8 ones;
#pragma unroll
    for (int i = 0; i < 8; ++i) ones[i] = (__bf16)1.0f;

    // PV both frags + l accumulation: VT frag shared
    __builtin_amdgcn_s_setprio(1);
    l_acc[0] = mfma_bf16(pa[0][0], ones, l_acc[0]);
    l_acc[0] = mfma_bf16(pa[0][1], ones, l_acc[0]);
    l_acc[1] = mfma_bf16(pa[1][0], ones, l_acc[1]);
    l_acc[1] = mfma_bf16(pa[1][1], ones, l_acc[1]);
#pragma unroll
    for (int n = 0; n < 4; ++n) {
#pragma unroll
      for (int t = 0; t < 2; ++t) {
        int rv = n * 16 + c;
        int byte = (rv * 128 + t * 64 + g * 16) ^ (((rv & 7) ^ ((rv >> 3) & 7)) << 4);
        bf16x8 vb = *reinterpret_cast<const bf16x8*>((const char*)Vc + byte);
        o[0][n] = mfma_bf16(pa[0][t], vb, o[0][n]);
        o[1][n] = mfma_bf16(pa[1][t], vb, o[1][n]);
      }
    }
    __builtin_amdgcn_s_setprio(0);
  };

  // ---- prologue: stage tile 0 into buffer 0; bias for tile 0
  stage_k(0, K_lds[0]);
  load_v(0);
  f32x4 bA = load_b(0), bB;
  write_v(VT[0]);
  __syncthreads();

  // ---- main loop, 2 tiles per iteration (static buffer indices)
  for (int kt = 0; kt < 32; kt += 2) {
    stage_k((kt + 1) * 64, K_lds[1]);
    load_v((kt + 1) * 64);
    bB = load_b((kt + 1) * 64);
    compute_tile(K_lds[0], VT[0], bA);
    write_v(VT[1]);
    __syncthreads();

    if (kt + 2 < 32) {
      stage_k((kt + 2) * 64, K_lds[0]);
      load_v((kt + 2) * 64);
      bA = load_b((kt + 2) * 64);
    }
    compute_tile(K_lds[1], VT[1], bB);
    if (kt + 2 < 32) write_v(VT[0]);
    __syncthreads();
  }

  // epilogue: x = O / l, write merged-head layout [B*S, D]
  // (l_acc holds sink + all tiles, replicated across lanes -- no reduce)
#pragma unroll
  for (int f = 0; f < 2; ++f)
#pragma unroll
    for (int j = 0; j < 4; ++j) {
      float inv = 1.f / l_acc[f][j];
      int q = q0 + f * 16 + g * 4 + j;
      size_t base = (bbase + q) * DD + h * DH + c;
#pragma unroll
      for (int n = 0; n < 4; ++n) {
        __bf16 hv = (__bf16)(o[f][n][j] * inv);
        Xbf[base + n * 16] = __builtin_bit_cast(unsigned short, hv);
      }
    }
}

// ---------------- launch ----------------
extern "C" void kernel_launch(void* const* d_in, const int* in_sizes, int n_in,
                              void* d_out, int out_size, void* d_ws, size_t ws_size,
                              hipStream_t stream) {
  const float* query = (const float*)d_in[0];
  const float* bias  = (const float*)d_in[1];
  const float* Wq = (const float*)d_in[2];
  const float* bq = (const float*)d_in[3];
  const float* Wk = (const float*)d_in[4];
  const float* bk = (const float*)d_in[5];
  const float* Wv = (const float*)d_in[6];
  const float* bv = (const float*)d_in[7];
  const float* Wo = (const float*)d_in[8];
  const float* bo = (const float*)d_in[9];
  const float* lk = (const float*)d_in[10];
  const float* lv = (const float*)d_in[11];

  char* ws = (char*)d_ws;
  unsigned short* Wqkv = (unsigned short*)(ws);                   //  6,291,456 B
  unsigned short* Wob  = (unsigned short*)(ws + 6291456);         //  2,097,152 B
  unsigned short* Qbf  = (unsigned short*)(ws + 8388608);         // 16,777,216 B
  unsigned short* Qh   = (unsigned short*)(ws + 25165824);        // 16,777,216 B
  unsigned short* Kh   = (unsigned short*)(ws + 41943040);        // 16,785,408 B
  unsigned short* Vh   = (unsigned short*)(ws + 58728448);        // 16,785,408 B
  float* biasL         = (float*)(ws + 75513856);                 //     32,768 B
  unsigned short* Xbf  = Qbf;  // Qbf dead after k_gemm_qkv; alias. total ~72 MiB
  float* out = (float*)d_out;

  k_prologue<<<12304, 256, 0, stream>>>(query, Wq, Wk, Wv, Wo, lk, lv, bias,
                                        Qbf, Wqkv, Wob, Kh, Vh, biasL);
  k_gemm_qkv<<<1536, 256, 0, stream>>>(Qbf, Wqkv, bq, bk, bv, Qh, Kh, Vh);
  k_attn<<<1024, 256, 0, stream>>>(Qh, Kh, Vh, biasL, Xbf);
  k_gemm_out<<<512, 256, 0, stream>>>(Xbf, Wob, bo, out);
}